// Round 4
// baseline (233.870 us; speedup 1.0000x reference)
//
#include <hip/hip_runtime.h>

#define C_DIM 28
#define HALF 14
#define HW 65536   // 256*256
#define THREADS 256
#define GRID 1024  // 1024 blocks * 256 thr * 4 px (2 hw x 2 b) = 16*65536 px exactly

namespace {

constexpr double K_PI = 3.14159265358979323846;

constexpr double cos_taylor(double u) {
    double u2 = u * u;
    double term = 1.0, sum = 1.0;
    for (int i = 1; i <= 12; ++i) {
        term *= -u2 / (double)((2 * i - 1) * (2 * i));
        sum += term;
    }
    return sum;
}

// cos(pi * t / 56), exact integer range reduction (period 112).
constexpr double cos_pi_over56(int t) {
    t %= 112;
    if (t < 0) t += 112;
    double sign = 1.0;
    if (t > 56) t = 112 - t;
    if (t > 28) { t = 56 - t; sign = -1.0; }
    return sign * cos_taylor(K_PI * (double)t / 56.0);
}

// Symmetry-folded tables.
// D[k][n]    = 2*cos(pi*(2n+1)k/56), n<14.  D[k][27-n] = (-1)^k D[k][n].
// Dinv[n][k] = cos(pi*(2n+1)k/56)*(k==0?0.5:1)/28, n<14.
//              Dinv[27-n][k] = (-1)^k Dinv[n][k].
struct Tables {
    float D[C_DIM][HALF];
    float Dinv[HALF][C_DIM];
};

constexpr Tables make_tables() {
    Tables t{};
    for (int k = 0; k < C_DIM; ++k)
        for (int n = 0; n < HALF; ++n)
            t.D[k][n] = (float)(2.0 * cos_pi_over56((2 * n + 1) * k));
    for (int n = 0; n < HALF; ++n)
        for (int k = 0; k < C_DIM; ++k)
            t.Dinv[n][k] = (float)(cos_pi_over56((2 * n + 1) * k) *
                                   ((k == 0) ? 0.5 : 1.0) / (double)C_DIM);
    return t;
}

constexpr Tables TBL = make_tables();

typedef float f2v __attribute__((ext_vector_type(2)));
typedef float f4v __attribute__((ext_vector_type(4)));

} // namespace

// Thread t handles FOUR pixels: (b0, hw0), (b0, hw0+1), (b0+8, hw0), (b0+8, hw0+1)
//   b0 = t >> 15 (0..7), hw0 = (t & 32767)*2.
// - dwordx2 x loads / stores (512 B per wave-instr, coalesced)
// - weight rows (448 B) loaded ONCE per 4 px -> w L2 traffic halved vs round 2/3
// - the two b-halves run SERIALLY (unroll 1) so pipeline registers are reused;
//   only w persists across halves -> ~95 VGPR -> 4+ waves/SIMD capacity
// - __launch_bounds__(256,4): cap VGPR at 128 so 4 blocks/CU (16 waves) reside
// - bijective XCD swizzle (1024 = 8*128): XCD k owns b-planes {k, k+8} exclusively
__global__ __launch_bounds__(THREADS, 4) void spedct_kernel(
    const float* __restrict__ x,
    const float* __restrict__ w,
    float* __restrict__ out) {

    // XCD-chunked bijective block swizzle: nwg=1024, 8 XCDs, 128 blocks each.
    const int bid = blockIdx.x;
    const int swz = (bid & 7) * 128 + (bid >> 3);

    const int t   = swz * THREADS + threadIdx.x;  // 0..262143
    const int b0  = t >> 15;                      // 0..7
    const int hw0 = (t & 32767) << 1;             // 0..65534, even

    // ---- weight rows hw0, hw0+1: 448 B contiguous = 14 dwordx4, once per 4 px.
    // Cached (w is reread by all 16 b-planes; keep L2/L3-resident).
    const f4v* wp4 = (const f4v*)(w + (size_t)hw0 * C_DIM);
    f4v w0[7], w1[7];
#pragma unroll
    for (int q = 0; q < 7; ++q) w0[q] = wp4[q];      // row hw0
#pragma unroll
    for (int q = 0; q < 7; ++q) w1[q] = wp4[7 + q];  // row hw0+1

    const float* xb = x   + (size_t)b0 * C_DIM * HW + hw0;
    float*       ob = out + (size_t)b0 * C_DIM * HW + hw0;

#pragma unroll 1   // keep halves serial: reuse pipeline registers, only w persists
    for (int half = 0; half < 2; ++half) {
        const float* xp = xb + (size_t)half * 8 * C_DIM * HW;  // b0 -> b0+8
        float*       op = ob + (size_t)half * 8 * C_DIM * HW;

        // ---- x: 28 dwordx2 NT loads (x read exactly once; don't pollute L3).
        f2v xv[C_DIM];
#pragma unroll
        for (int n = 0; n < C_DIM; ++n)
            xv[n] = __builtin_nontemporal_load((const f2v*)(xp + (size_t)n * HW));

        // ---- fold: s[n] = x[n]+x[27-n], u[n] = x[n]-x[27-n]
        f2v s[HALF], u[HALF];
#pragma unroll
        for (int n = 0; n < HALF; ++n) {
            s[n].x = xv[n].x + xv[27 - n].x;
            s[n].y = xv[n].y + xv[27 - n].y;
            u[n].x = xv[n].x - xv[27 - n].x;
            u[n].y = xv[n].y - xv[27 - n].y;
        }

        // ---- forward: Xd = D*x via fold. Even k uses s, odd k uses u.
        f2v xd[C_DIM];
#pragma unroll
        for (int k = 0; k < C_DIM; ++k) {
            const float c = TBL.D[k][0];
            xd[k].x = c * ((k & 1) ? u[0].x : s[0].x);
            xd[k].y = c * ((k & 1) ? u[0].y : s[0].y);
        }
#pragma unroll
        for (int n = 1; n < HALF; ++n) {
#pragma unroll
            for (int k = 0; k < C_DIM; ++k) {
                const float c = TBL.D[k][n];
                if (k & 1) {
                    xd[k].x = fmaf(c, u[n].x, xd[k].x);
                    xd[k].y = fmaf(c, u[n].y, xd[k].y);
                } else {
                    xd[k].x = fmaf(c, s[n].x, xd[k].x);
                    xd[k].y = fmaf(c, s[n].y, xd[k].y);
                }
            }
        }

        // ---- spectral filter (per-pixel weight row; same rows for both halves).
#pragma unroll
        for (int q = 0; q < 7; ++q) {
#pragma unroll
            for (int i = 0; i < 4; ++i) {
                xd[4 * q + i].x *= w0[q][i];
                xd[4 * q + i].y *= w1[q][i];
            }
        }

        // ---- inverse: o = Dinv*xd via fold; o[n]=e+f, o[27-n]=e-f.
        f2v e[HALF], f[HALF];
#pragma unroll
        for (int n = 0; n < HALF; ++n) {
            e[n].x = TBL.Dinv[n][0] * xd[0].x;
            e[n].y = TBL.Dinv[n][0] * xd[0].y;
            f[n].x = TBL.Dinv[n][1] * xd[1].x;
            f[n].y = TBL.Dinv[n][1] * xd[1].y;
        }
#pragma unroll
        for (int j = 1; j < HALF; ++j) {
#pragma unroll
            for (int n = 0; n < HALF; ++n) {
                const float ce = TBL.Dinv[n][2 * j];
                const float cf = TBL.Dinv[n][2 * j + 1];
                e[n].x = fmaf(ce, xd[2 * j].x, e[n].x);
                e[n].y = fmaf(ce, xd[2 * j].y, e[n].y);
                f[n].x = fmaf(cf, xd[2 * j + 1].x, f[n].x);
                f[n].y = fmaf(cf, xd[2 * j + 1].y, f[n].y);
            }
        }

        // ---- stores: 28 normal dwordx2 (flavor proven irrelevant r2 vs r3).
#pragma unroll
        for (int n = 0; n < HALF; ++n) {
            f2v lo, hi;
            lo.x = e[n].x + f[n].x;  lo.y = e[n].y + f[n].y;
            hi.x = e[n].x - f[n].x;  hi.y = e[n].y - f[n].y;
            *(f2v*)(op + (size_t)n * HW) = lo;
            *(f2v*)(op + (size_t)(27 - n) * HW) = hi;
        }
    }
}

extern "C" void kernel_launch(void* const* d_in, const int* in_sizes, int n_in,
                              void* d_out, int out_size, void* d_ws, size_t ws_size,
                              hipStream_t stream) {
    const float* x = (const float*)d_in[0];   // [16,28,256,256]
    const float* w = (const float*)d_in[1];   // [256,256,28]
    float* out = (float*)d_out;               // [16,28,256,256]

    spedct_kernel<<<dim3(GRID), dim3(THREADS), 0, stream>>>(x, w, out);
}

// Round 6
// 211.118 us; speedup vs baseline: 1.1078x; 1.1078x over previous
//
#include <hip/hip_runtime.h>

#define C_DIM 28
#define HALF 14
#define HW 65536   // 256*256
#define THREADS 256
#define GRID 2048  // 2048*256 threads * 2 consecutive px = 16*65536 pixels exactly

namespace {

constexpr double K_PI = 3.14159265358979323846;

constexpr double cos_taylor(double u) {
    double u2 = u * u;
    double term = 1.0, sum = 1.0;
    for (int i = 1; i <= 12; ++i) {
        term *= -u2 / (double)((2 * i - 1) * (2 * i));
        sum += term;
    }
    return sum;
}

// cos(pi * t / 56), exact integer range reduction (period 112).
constexpr double cos_pi_over56(int t) {
    t %= 112;
    if (t < 0) t += 112;
    double sign = 1.0;
    if (t > 56) t = 112 - t;
    if (t > 28) { t = 56 - t; sign = -1.0; }
    return sign * cos_taylor(K_PI * (double)t / 56.0);
}

// Symmetry-folded tables.
// D[k][n]    = 2*cos(pi*(2n+1)k/56), n<14.  D[k][27-n] = (-1)^k D[k][n].
// Dinv[n][k] = cos(pi*(2n+1)k/56)*(k==0?0.5:1)/28, n<14.
//              Dinv[27-n][k] = (-1)^k Dinv[n][k].
struct Tables {
    float D[C_DIM][HALF];
    float Dinv[HALF][C_DIM];
};

constexpr Tables make_tables() {
    Tables t{};
    for (int k = 0; k < C_DIM; ++k)
        for (int n = 0; n < HALF; ++n)
            t.D[k][n] = (float)(2.0 * cos_pi_over56((2 * n + 1) * k));
    for (int n = 0; n < HALF; ++n)
        for (int k = 0; k < C_DIM; ++k)
            t.Dinv[n][k] = (float)(cos_pi_over56((2 * n + 1) * k) *
                                   ((k == 0) ? 0.5 : 1.0) / (double)C_DIM);
    return t;
}

constexpr Tables TBL = make_tables();

typedef float f2v __attribute__((ext_vector_type(2)));
typedef float f4v __attribute__((ext_vector_type(4)));

} // namespace

// Thread t handles two CONSECUTIVE pixels (b, hw0) and (b, hw0+1):
//   b = t >> 15, hw0 = (t & 32767)*2.  (identical traversal to round 3 —
//   this ordering measured FETCH=62.5 MB, i.e. L3 keeps half of x resident;
//   round 4's reordering blew it up to 138 MB. Do not touch.)
//
// Round-5/6 single variable: FORCE all 28 x-loads into flight before any fold
// math. Round 3's compiler schedule (76 VGPR, register-minimizing) emitted
// ~14 sequential load-pair -> wait -> fold cycles = ~9 us/block of pure
// latency chain. The asm memory fence makes all 28 load results live
// simultaneously (one latency total); __launch_bounds__(256,2) raises the
// VGPR cap to 256 so the forced liveness doesn't spill.
__global__ __launch_bounds__(THREADS, 2) void spedct_kernel(
    const float* __restrict__ x,
    const float* __restrict__ w,
    float* __restrict__ out) {

    const int t   = blockIdx.x * THREADS + threadIdx.x;  // 0..524287
    const int b   = t >> 15;                             // 0..15
    const int hw0 = (t & 32767) << 1;                    // 0..65534, even

    const float* xp = x   + (size_t)b * C_DIM * HW + hw0;
    float*       op = out + (size_t)b * C_DIM * HW + hw0;

    // ---- x: 28 dwordx2 NT loads, ALL issued before the fence.
    f2v xv[C_DIM];
#pragma unroll
    for (int n = 0; n < C_DIM; ++n)
        xv[n] = __builtin_nontemporal_load((const f2v*)(xp + (size_t)n * HW));

    // Batch-issue fence: no load may sink below, no use may hoist above.
    // All 28 loads (56 VGPRs) are in flight here -> one memory latency.
    asm volatile("" ::: "memory");

    // ---- fold: s[n] = x[n]+x[27-n], u[n] = x[n]-x[27-n]
    f2v s[HALF], u[HALF];
#pragma unroll
    for (int n = 0; n < HALF; ++n) {
        s[n].x = xv[n].x + xv[27 - n].x;
        s[n].y = xv[n].y + xv[27 - n].y;
        u[n].x = xv[n].x - xv[27 - n].x;
        u[n].y = xv[n].y - xv[27 - n].y;
    }

    // ---- weight rows hw0, hw0+1: 448 B contiguous = 14 dwordx4.
    // Issued after the fence: their latency hides under the forward-DCT FMAs.
    // Cached (w is reread by all 16 b-planes; keep L2/L3-resident).
    const f4v* wp4 = (const f4v*)(w + (size_t)hw0 * C_DIM);
    f4v w0[7], w1[7];
#pragma unroll
    for (int q = 0; q < 7; ++q) w0[q] = wp4[q];      // row hw0
#pragma unroll
    for (int q = 0; q < 7; ++q) w1[q] = wp4[7 + q];  // row hw0+1

    // ---- forward: Xd = D*x via fold. Even k uses s, odd k uses u.
    f2v xd[C_DIM];
#pragma unroll
    for (int k = 0; k < C_DIM; ++k) {
        const float c = TBL.D[k][0];
        xd[k].x = c * ((k & 1) ? u[0].x : s[0].x);
        xd[k].y = c * ((k & 1) ? u[0].y : s[0].y);
    }
#pragma unroll
    for (int n = 1; n < HALF; ++n) {
#pragma unroll
        for (int k = 0; k < C_DIM; ++k) {
            const float c = TBL.D[k][n];
            if (k & 1) {
                xd[k].x = fmaf(c, u[n].x, xd[k].x);
                xd[k].y = fmaf(c, u[n].y, xd[k].y);
            } else {
                xd[k].x = fmaf(c, s[n].x, xd[k].x);
                xd[k].y = fmaf(c, s[n].y, xd[k].y);
            }
        }
    }

    // ---- spectral filter: per-pixel weight row (register "transpose" free).
#pragma unroll
    for (int q = 0; q < 7; ++q) {
#pragma unroll
        for (int i = 0; i < 4; ++i) {
            xd[4 * q + i].x *= w0[q][i];
            xd[4 * q + i].y *= w1[q][i];
        }
    }

    // ---- inverse: o = Dinv*xd via fold; o[n]=e+f, o[27-n]=e-f.
    f2v e[HALF], f[HALF];
#pragma unroll
    for (int n = 0; n < HALF; ++n) {
        e[n].x = TBL.Dinv[n][0] * xd[0].x;
        e[n].y = TBL.Dinv[n][0] * xd[0].y;
        f[n].x = TBL.Dinv[n][1] * xd[1].x;
        f[n].y = TBL.Dinv[n][1] * xd[1].y;
    }
#pragma unroll
    for (int j = 1; j < HALF; ++j) {
#pragma unroll
        for (int n = 0; n < HALF; ++n) {
            const float ce = TBL.Dinv[n][2 * j];
            const float cf = TBL.Dinv[n][2 * j + 1];
            e[n].x = fmaf(ce, xd[2 * j].x, e[n].x);
            e[n].y = fmaf(ce, xd[2 * j].y, e[n].y);
            f[n].x = fmaf(cf, xd[2 * j + 1].x, f[n].x);
            f[n].y = fmaf(cf, xd[2 * j + 1].y, f[n].y);
        }
    }

    // ---- stores: 28 dwordx2 (flavor proven irrelevant r2 vs r3).
#pragma unroll
    for (int n = 0; n < HALF; ++n) {
        f2v lo, hi;
        lo.x = e[n].x + f[n].x;  lo.y = e[n].y + f[n].y;
        hi.x = e[n].x - f[n].x;  hi.y = e[n].y - f[n].y;
        *(f2v*)(op + (size_t)n * HW) = lo;
        *(f2v*)(op + (size_t)(27 - n) * HW) = hi;
    }
}

extern "C" void kernel_launch(void* const* d_in, const int* in_sizes, int n_in,
                              void* d_out, int out_size, void* d_ws, size_t ws_size,
                              hipStream_t stream) {
    const float* x = (const float*)d_in[0];   // [16,28,256,256]
    const float* w = (const float*)d_in[1];   // [256,256,28]
    float* out = (float*)d_out;               // [16,28,256,256]

    spedct_kernel<<<dim3(GRID), dim3(THREADS), 0, stream>>>(x, w, out);
}